// Round 4
// baseline (3054.175 us; speedup 1.0000x reference)
//
#include <hip/hip_runtime.h>
#include <hip/hip_bf16.h>

// Sizes (fixed): T=512 tokens, D=256 embed, L=256 lstm, H=512 hidden. 4L=1024.

typedef _Float16 h2v __attribute__((ext_vector_type(2)));
typedef unsigned int u32x8 __attribute__((ext_vector_type(8)));

#define BC(x) __builtin_bit_cast(h2v, (x))

__device__ __forceinline__ float fdot2f(h2v a, h2v b, float c) {
#if __has_builtin(__builtin_amdgcn_fdot2)
    return __builtin_amdgcn_fdot2(a, b, c, false);
#else
    return c + (float)a[0] * (float)b[0] + (float)a[1] * (float)b[1];
#endif
}

// ---------------------------------------------------------------------------
// prep_u: U [256 x 1024] f32 row-major -> packed half2 per (k-pair, col)
// Uf[k2*1024 + col] = (U[2k2][col], U[2k2+1][col]) as 2xf16 in a uint
// ---------------------------------------------------------------------------
__global__ __launch_bounds__(256) void prep_u(const float* __restrict__ U,
                                              unsigned int* __restrict__ Uf) {
    int idx = blockIdx.x * 256 + threadIdx.x;  // < 131072
    int k2 = idx >> 10, col = idx & 1023;
    union { _Float16 h[2]; unsigned int u; } p;
    p.h[0] = (_Float16)U[(2 * k2) * 1024 + col];
    p.h[1] = (_Float16)U[(2 * k2 + 1) * 1024 + col];
    Uf[idx] = p.u;
}

// ---------------------------------------------------------------------------
// Generic f32 GEMM: C[M,N] = opA(A)[M,K] @ B[K,N] + bias[N]
// ---------------------------------------------------------------------------
__global__ __launch_bounds__(256) void gemm_bias(const float* __restrict__ A,
                                                 const float* __restrict__ B,
                                                 const float* __restrict__ bias,
                                                 float* __restrict__ C,
                                                 int M, int N, int K, int revA) {
    __shared__ float sA[16][65];
    __shared__ float sB[16][65];
    int tid = threadIdx.x;
    int bm = blockIdx.y * 64, bn = blockIdx.x * 64;
    int tx = tid & 15, ty = tid >> 4;
    float acc[4][4] = {};
    for (int k0 = 0; k0 < K; k0 += 16) {
#pragma unroll
        for (int l = 0; l < 4; l++) {
            int flat = tid + 256 * l;
            int ml = flat >> 4, kk = flat & 15;
            int row = bm + ml;
            if (revA) row = M - 1 - row;
            sA[kk][ml] = A[row * K + k0 + kk];
        }
#pragma unroll
        for (int l = 0; l < 4; l++) {
            int flat = tid + 256 * l;
            int kk = flat >> 6, nl = flat & 63;
            sB[kk][nl] = B[(k0 + kk) * N + bn + nl];
        }
        __syncthreads();
#pragma unroll
        for (int kk = 0; kk < 16; kk++) {
            float a[4], b[4];
#pragma unroll
            for (int i = 0; i < 4; i++) a[i] = sA[kk][ty + 16 * i];
#pragma unroll
            for (int j = 0; j < 4; j++) b[j] = sB[kk][tx + 16 * j];
#pragma unroll
            for (int i = 0; i < 4; i++)
#pragma unroll
                for (int j = 0; j < 4; j++) acc[i][j] += a[i] * b[j];
        }
        __syncthreads();
    }
#pragma unroll
    for (int i = 0; i < 4; i++) {
        int r = bm + ty + 16 * i;
#pragma unroll
        for (int j = 0; j < 4; j++) {
            int cidx = bn + tx + 16 * j;
            float bv = bias ? bias[cidx] : 0.f;
            C[r * N + cidx] = acc[i][j] + bv;
        }
    }
}

// ---------------------------------------------------------------------------
// lstm_quad: 8 blocks (4 per direction) x 256 threads.
//
// Wall hit by rounds 0-3 (all ~1170-1200us): one CU per direction can keep at
// most 147KB (LDS) of the 512KB U on-chip; the allocator's real VGPR budget
// (128@512thr, 64@1024thr — it assumes 2 blocks/CU occupancy regardless of
// waves_per_eu/LDS) spills any big register tile, so >=365KB/step streams
// from L2 at the ~60-70B/cyc/CU fill rate = ~6000cyc/step. Structural.
//
// Fix: 4 blocks per direction. Block b owns hidden units [64b,64b+64) and ALL
// FOUR gate columns of those units (col = 256*gate + 64*b + u), so gates are
// computed locally and blocks exchange only h (256 f16 = 512B/step total).
//   U-slice/block = 128 kp x 256 cols: kp[0,64) in LDS (64KB),
//   kp[64,128) in 8 x u32x8 = 64 VGPRs (total ~100 regs; fits even a
//   pessimistic 128 grant). NOTHING streams from L2 in the step loop.
// Cross-block handshake per step: pack h-pairs -> global parity buffer
// (double-buffered by step parity: a one-step-ahead block writes the OTHER
// buffer, so no overwrite race) -> release atomicAdd on agent-scope counter
// -> lane-0 spin acquire-load until 4 arrivals -> gather 128 uints from LLC.
// Co-residency: 8 blocks on a 256-CU chip. Counter memset per dispatch.
// ---------------------------------------------------------------------------
#define UAq(r) ((r) < 8 ? q0[(r) & 7] : (r) < 16 ? q1[(r) & 7] : \
                (r) < 24 ? q2[(r) & 7] : (r) < 32 ? q3[(r) & 7] : \
                (r) < 40 ? q4[(r) & 7] : (r) < 48 ? q5[(r) & 7] : \
                (r) < 56 ? q6[(r) & 7] : q7[(r) & 7])

__global__ __launch_bounds__(256) void lstm_quad(
        const unsigned int* __restrict__ Ua, const unsigned int* __restrict__ Ub,
        const float* __restrict__ Pa, const float* __restrict__ Pb,
        float* __restrict__ Oa, float* __restrict__ Ob,
        unsigned int* ctrs, unsigned int* Hg) {
    int dir = blockIdx.x >> 2;  // 0 = fwd, 1 = bwd
    int b = blockIdx.x & 3;     // owns hidden units [64b, 64b+64)
    const unsigned int* U = dir ? Ub : Ua;
    const float* P = dir ? Pb : Pa;
    float* O = dir ? Ob : Oa;
    unsigned int* ctr = ctrs + dir;
    unsigned int* Hgd = Hg + dir * 256;  // 2 parity buffers x 128 uints

    __shared__ unsigned int sU[64 * 256];            // 65536 B, kp-major slice
    __shared__ __align__(16) unsigned int sH[128];   // h as packed f16 pairs
    __shared__ float sZ[256];
    __shared__ float sG[64];

    int t = threadIdx.x;  // 0..255
    // gate g = t>>6, unit u = t&63; global column in the 4L z-vector:
    int col = ((t >> 6) << 8) + (b << 6) + (t & 63);

    // stage kp [0,64) of this block's 256 columns into LDS
    for (int kp = 0; kp < 64; kp++) sU[kp * 256 + t] = U[kp * 1024 + col];

    // kp [64,128) register-resident: 8 x 8-wide SSA vectors = 64 VGPRs
    u32x8 q0, q1, q2, q3, q4, q5, q6, q7;
#pragma unroll
    for (int j = 0; j < 8; j++) {
        q0[j] = U[(64 + j) * 1024 + col];
        q1[j] = U[(72 + j) * 1024 + col];
        q2[j] = U[(80 + j) * 1024 + col];
        q3[j] = U[(88 + j) * 1024 + col];
        q4[j] = U[(96 + j) * 1024 + col];
        q5[j] = U[(104 + j) * 1024 + col];
        q6[j] = U[(112 + j) * 1024 + col];
        q7[j] = U[(120 + j) * 1024 + col];
    }
    asm volatile(""
                 : "+v"(q0), "+v"(q1), "+v"(q2), "+v"(q3),
                   "+v"(q4), "+v"(q5), "+v"(q6), "+v"(q7));

    if (t < 128) sH[t] = 0u;
    float c = 0.f;
    __syncthreads();

    const uint4* hp4 = (const uint4*)sH;  // 32 chunks x (4 h2v) = 256 h
    float pc = P[col];
    for (int step = 0; step < 512; step++) {
        float pn = pc;
        if (step < 511) pn = P[(step + 1) * 1024 + col];
        float a0 = pc, a1 = 0.f, a2 = 0.f, a3 = 0.f;  // 4 indep dep-chains

        // kp [0,64) from LDS (lane-consecutive b32, conflict-free)
#pragma unroll
        for (int cch = 0; cch < 16; cch++) {
            uint4 hc = hp4[cch];
            const unsigned int* su = &sU[(4 * cch) * 256 + t];
            a0 = fdot2f(BC(hc.x), BC(su[0]), a0);
            a1 = fdot2f(BC(hc.y), BC(su[256]), a1);
            a2 = fdot2f(BC(hc.z), BC(su[512]), a2);
            a3 = fdot2f(BC(hc.w), BC(su[768]), a3);
        }
        // kp [64,128) from registers
#pragma unroll
        for (int cch = 16; cch < 32; cch++) {
            uint4 hc = hp4[cch];
            const int r0 = 4 * (cch - 16);
            a0 = fdot2f(BC(hc.x), BC(UAq(r0 + 0)), a0);
            a1 = fdot2f(BC(hc.y), BC(UAq(r0 + 1)), a1);
            a2 = fdot2f(BC(hc.z), BC(UAq(r0 + 2)), a2);
            a3 = fdot2f(BC(hc.w), BC(UAq(r0 + 3)), a3);
        }
        sZ[t] = (a0 + a1) + (a2 + a3);
        __syncthreads();

        unsigned int* Hbuf = Hgd + ((step + 1) & 1) * 128;  // parity dbuf
        if (t < 64) {
            float zi = sZ[t], zf = sZ[64 + t], zg = sZ[128 + t], zo = sZ[192 + t];
            float ig = 1.f / (1.f + __expf(-zi));
            float fg = 1.f / (1.f + __expf(-zf));
            float gg = 1.f - 2.f / (1.f + __expf(2.f * zg));   // tanh
            float og = 1.f / (1.f + __expf(-zo));
            c = fg * c + ig * gg;
            float h = og * (1.f - 2.f / (1.f + __expf(2.f * c)));
            O[step * 256 + (b << 6) + t] = h;
            sG[t] = h;  // wave 0 only: LDS ops below are same-wave ordered
            if (t < 32) {
                union { _Float16 hh[2]; unsigned int u; } pk;
                pk.hh[0] = (_Float16)sG[2 * t];
                pk.hh[1] = (_Float16)sG[2 * t + 1];
                Hbuf[(b << 5) + t] = pk.u;
            }
            if (t == 0)
                __hip_atomic_fetch_add(ctr, 1u, __ATOMIC_RELEASE,
                                       __HIP_MEMORY_SCOPE_AGENT);
        }
        if (t == 0) {
            unsigned int target = 4u * (step + 1);
            while (__hip_atomic_load(ctr, __ATOMIC_ACQUIRE,
                                     __HIP_MEMORY_SCOPE_AGENT) < target) {}
        }
        __syncthreads();
        if (t < 128) sH[t] = Hbuf[t];  // gather all 4 blocks' h-pairs
        __syncthreads();
        pc = pn;
    }
}

// ---------------------------------------------------------------------------
// concat: V[t][0:256] = F[t], V[t][256:512] = Bk[511-t]
// ---------------------------------------------------------------------------
__global__ __launch_bounds__(256) void concat_k(const float* __restrict__ F,
                                                const float* __restrict__ Bk,
                                                float* __restrict__ V) {
    int idx = blockIdx.x * 256 + threadIdx.x;  // < 262144
    int t = idx >> 9, d = idx & 511;
    V[idx] = (d < 256) ? F[t * 256 + d] : Bk[(511 - t) * 256 + d - 256];
}

// ---------------------------------------------------------------------------
// head: S[i][j] = sum_h tanh(HF[i][h] + MF[j][h]) * w[h] + outBias
// ---------------------------------------------------------------------------
__global__ __launch_bounds__(256) void head_kernel(const float* __restrict__ HF,
                                                   const float* __restrict__ MF,
                                                   const float* __restrict__ w,
                                                   const float* __restrict__ outb,
                                                   float* __restrict__ S) {
    int i = blockIdx.x;
    __shared__ float sHF[512], sW[512];
    int tid = threadIdx.x;
    sHF[tid] = HF[i * 512 + tid];
    sHF[tid + 256] = HF[i * 512 + 256 + tid];
    sW[tid] = w[tid];
    sW[tid + 256] = w[tid + 256];
    __syncthreads();
    int lane = tid & 63, wv = tid >> 6;
    float ob = outb[0];
    for (int j = wv; j < 512; j += 4) {
        const float* mf = MF + j * 512;
        float acc = 0.f;
#pragma unroll
        for (int r = 0; r < 8; r++) {
            int h = lane + 64 * r;
            float x = sHF[h] + mf[h];
            acc += sW[h] * (1.f - 2.f / (1.f + __expf(2.f * x)));
        }
#pragma unroll
        for (int off = 32; off; off >>= 1) acc += __shfl_down(acc, off);
        if (lane == 0) S[i * 512 + j] = acc + ob;
    }
}

// ---------------------------------------------------------------------------
extern "C" void kernel_launch(void* const* d_in, const int* in_sizes, int n_in,
                              void* d_out, int out_size, void* d_ws, size_t ws_size,
                              hipStream_t stream) {
    const float* emb      = (const float*)d_in[0];
    const float* W_f1     = (const float*)d_in[1];
    const float* U_f1     = (const float*)d_in[2];
    const float* b_f1     = (const float*)d_in[3];
    const float* W_b1     = (const float*)d_in[4];
    const float* U_b1     = (const float*)d_in[5];
    const float* b_b1     = (const float*)d_in[6];
    const float* W_f2     = (const float*)d_in[7];
    const float* U_f2     = (const float*)d_in[8];
    const float* b_f2     = (const float*)d_in[9];
    const float* W_b2     = (const float*)d_in[10];
    const float* U_b2     = (const float*)d_in[11];
    const float* b_b2     = (const float*)d_in[12];
    const float* FOH      = (const float*)d_in[13];
    const float* FOM      = (const float*)d_in[14];
    const float* hidBias  = (const float*)d_in[15];
    const float* outLayer = (const float*)d_in[16];
    const float* outBias  = (const float*)d_in[17];
    float* out = (float*)d_out;

    // workspace carve (16 MB total, exactly full)
    unsigned int* uf = (unsigned int*)d_ws;          // 4 x 131072 uints = 2MB
    unsigned int* uf_f1 = uf;
    unsigned int* uf_b1 = uf + 131072;
    unsigned int* uf_f2 = uf + 262144;
    unsigned int* uf_b2 = uf + 393216;
    float* f = (float*)d_ws + 524288;
    float* P1f = f;                 // 512x1024
    float* P1b = f + 524288;
    float* P2f = f + 1048576;
    float* P2b = f + 1572864;
    float* rf1 = f + 2097152;       // 512x256
    float* rb1 = f + 2228224;
    float* rf2 = f + 2359296;
    float* rb2 = f + 2490368;
    float* v    = f + 2621440;      // 512x512
    float* hcat = f + 2883584;
    float* HFb  = f + 3145728;      // 512x512 (includes hidBias)
    float* MFb  = f + 3407872;
    // sync region aliases MFb (dead during both lstm dispatches: MFb is only
    // written by the 2nd-to-last gemm and read by head, both after lstm-2)
    unsigned int* sync = (unsigned int*)(f + 3407872);  // ctr[4] + Hg[512]

    prep_u<<<512, 256, 0, stream>>>(U_f1, uf_f1);
    prep_u<<<512, 256, 0, stream>>>(U_b1, uf_b1);
    prep_u<<<512, 256, 0, stream>>>(U_f2, uf_f2);
    prep_u<<<512, 256, 0, stream>>>(U_b2, uf_b2);

    dim3 g1(1024 / 64, 512 / 64);
    gemm_bias<<<g1, 256, 0, stream>>>(emb, W_f1, b_f1, P1f, 512, 1024, 256, 0);
    gemm_bias<<<g1, 256, 0, stream>>>(emb, W_b1, b_b1, P1b, 512, 1024, 256, 1);

    hipMemsetAsync(sync, 0, 16, stream);
    lstm_quad<<<8, 256, 0, stream>>>(uf_f1, uf_b1, P1f, P1b, rf1, rb1,
                                     sync, sync + 4);

    concat_k<<<1024, 256, 0, stream>>>(rf1, rb1, v);

    gemm_bias<<<g1, 256, 0, stream>>>(v, W_f2, b_f2, P2f, 512, 1024, 512, 0);
    gemm_bias<<<g1, 256, 0, stream>>>(v, W_b2, b_b2, P2b, 512, 1024, 512, 1);

    hipMemsetAsync(sync, 0, 16, stream);
    lstm_quad<<<8, 256, 0, stream>>>(uf_f2, uf_b2, P2f, P2b, rf2, rb2,
                                     sync, sync + 4);

    concat_k<<<1024, 256, 0, stream>>>(rf2, rb2, hcat);

    dim3 g2(512 / 64, 512 / 64);
    gemm_bias<<<g2, 256, 0, stream>>>(hcat, FOH, hidBias, HFb, 512, 512, 512, 0);
    gemm_bias<<<g2, 256, 0, stream>>>(hcat, FOM, nullptr, MFb, 512, 512, 512, 0);

    head_kernel<<<512, 256, 0, stream>>>(HFb, MFb, outLayer, outBias, out);
}

// Round 5
// 2420.428 us; speedup vs baseline: 1.2618x; 1.2618x over previous
//
#include <hip/hip_runtime.h>
#include <hip/hip_bf16.h>

// Sizes (fixed): T=512 tokens, D=256 embed, L=256 lstm, H=512 hidden. 4L=1024.

typedef _Float16 h2v __attribute__((ext_vector_type(2)));
typedef unsigned int u32x8 __attribute__((ext_vector_type(8)));

#define BC(x) __builtin_bit_cast(h2v, (x))

__device__ __forceinline__ float fdot2f(h2v a, h2v b, float c) {
#if __has_builtin(__builtin_amdgcn_fdot2)
    return __builtin_amdgcn_fdot2(a, b, c, false);
#else
    return c + (float)a[0] * (float)b[0] + (float)a[1] * (float)b[1];
#endif
}

// ---------------------------------------------------------------------------
// prep_u: U [256 x 1024] f32 row-major -> packed half2 per (k-pair, col)
// Uf[k2*1024 + col] = (U[2k2][col], U[2k2+1][col]) as 2xf16 in a uint
// ---------------------------------------------------------------------------
__global__ __launch_bounds__(256) void prep_u(const float* __restrict__ U,
                                              unsigned int* __restrict__ Uf) {
    int idx = blockIdx.x * 256 + threadIdx.x;  // < 131072
    int k2 = idx >> 10, col = idx & 1023;
    union { _Float16 h[2]; unsigned int u; } p;
    p.h[0] = (_Float16)U[(2 * k2) * 1024 + col];
    p.h[1] = (_Float16)U[(2 * k2 + 1) * 1024 + col];
    Uf[idx] = p.u;
}

// ---------------------------------------------------------------------------
// Generic f32 GEMM: C[M,N] = opA(A)[M,K] @ B[K,N] + bias[N]
// ---------------------------------------------------------------------------
__global__ __launch_bounds__(256) void gemm_bias(const float* __restrict__ A,
                                                 const float* __restrict__ B,
                                                 const float* __restrict__ bias,
                                                 float* __restrict__ C,
                                                 int M, int N, int K, int revA) {
    __shared__ float sA[16][65];
    __shared__ float sB[16][65];
    int tid = threadIdx.x;
    int bm = blockIdx.y * 64, bn = blockIdx.x * 64;
    int tx = tid & 15, ty = tid >> 4;
    float acc[4][4] = {};
    for (int k0 = 0; k0 < K; k0 += 16) {
#pragma unroll
        for (int l = 0; l < 4; l++) {
            int flat = tid + 256 * l;
            int ml = flat >> 4, kk = flat & 15;
            int row = bm + ml;
            if (revA) row = M - 1 - row;
            sA[kk][ml] = A[row * K + k0 + kk];
        }
#pragma unroll
        for (int l = 0; l < 4; l++) {
            int flat = tid + 256 * l;
            int kk = flat >> 6, nl = flat & 63;
            sB[kk][nl] = B[(k0 + kk) * N + bn + nl];
        }
        __syncthreads();
#pragma unroll
        for (int kk = 0; kk < 16; kk++) {
            float a[4], b[4];
#pragma unroll
            for (int i = 0; i < 4; i++) a[i] = sA[kk][ty + 16 * i];
#pragma unroll
            for (int j = 0; j < 4; j++) b[j] = sB[kk][tx + 16 * j];
#pragma unroll
            for (int i = 0; i < 4; i++)
#pragma unroll
                for (int j = 0; j < 4; j++) acc[i][j] += a[i] * b[j];
        }
        __syncthreads();
    }
#pragma unroll
    for (int i = 0; i < 4; i++) {
        int r = bm + ty + 16 * i;
#pragma unroll
        for (int j = 0; j < 4; j++) {
            int cidx = bn + tx + 16 * j;
            float bv = bias ? bias[cidx] : 0.f;
            C[r * N + cidx] = acc[i][j] + bv;
        }
    }
}

// ---------------------------------------------------------------------------
// lstm_quad: 8 blocks (4 per direction) x 256 threads.
//
// Capacity (round 4, works): block b owns hidden units [64b,64b+64) and all
// four gate columns of those units (col = 256*gate + 64*b + u). U-slice =
// 128kp x 256 cols: kp[0,64) in LDS (64KB), kp[64,128) in 8 x u32x8 = 64
// VGPRs (VGPR_Count=88, no spill). Nothing streams from L2 in the step loop.
//
// Sync (round-4 post-mortem, this round's fix): the counter+release/acquire
// handshake serialized THREE agent-scope LLC round trips per step and its
// acquire invalidated L1/L2 every step (FETCH_SIZE 2.5->4MB from P
// re-fetches; 2.3us/step sync). Replaced by single-round-trip tagged
// entries: each h-pair publishes as ONE 8-byte relaxed agent-scope atomic
// {tag=step+1 | packed f16 pair} in a parity-double-buffered slot; readers
// poll their own entry until the tag matches -- tag+data in the same load,
// no fences, no cache maintenance. Parity safety: a writer reuses a slot 2
// steps later, and writing tag s+2 proves (via its own poll of peers' s+2
// tags) every peer consumed its s+1 entry. Stale tags zeroed by 4KB memset
// per dispatch.
// ---------------------------------------------------------------------------
#define UAq(r) ((r) < 8 ? q0[(r) & 7] : (r) < 16 ? q1[(r) & 7] : \
                (r) < 24 ? q2[(r) & 7] : (r) < 32 ? q3[(r) & 7] : \
                (r) < 40 ? q4[(r) & 7] : (r) < 48 ? q5[(r) & 7] : \
                (r) < 56 ? q6[(r) & 7] : q7[(r) & 7])

__global__ __launch_bounds__(256) void lstm_quad(
        const unsigned int* __restrict__ Ua, const unsigned int* __restrict__ Ub,
        const float* __restrict__ Pa, const float* __restrict__ Pb,
        float* __restrict__ Oa, float* __restrict__ Ob,
        unsigned long long* Hg) {
    int dir = blockIdx.x >> 2;  // 0 = fwd, 1 = bwd
    int b = blockIdx.x & 3;     // owns hidden units [64b, 64b+64)
    const unsigned int* U = dir ? Ub : Ua;
    const float* P = dir ? Pb : Pa;
    float* O = dir ? Ob : Oa;
    // per dir: 2 parity buffers x 128 entries (4 blocks x 32 h-pairs)
    unsigned long long* Hgd = Hg + dir * 256;

    __shared__ unsigned int sU[64 * 256];            // 65536 B, kp-major slice
    __shared__ __align__(16) unsigned int sH[128];   // h as packed f16 pairs
    __shared__ float sZ[256];
    __shared__ float sG[64];

    int t = threadIdx.x;  // 0..255
    // gate g = t>>6, unit u = t&63; global column in the 4L z-vector:
    int col = ((t >> 6) << 8) + (b << 6) + (t & 63);

    // stage kp [0,64) of this block's 256 columns into LDS
    for (int kp = 0; kp < 64; kp++) sU[kp * 256 + t] = U[kp * 1024 + col];

    // kp [64,128) register-resident: 8 x 8-wide SSA vectors = 64 VGPRs
    u32x8 q0, q1, q2, q3, q4, q5, q6, q7;
#pragma unroll
    for (int j = 0; j < 8; j++) {
        q0[j] = U[(64 + j) * 1024 + col];
        q1[j] = U[(72 + j) * 1024 + col];
        q2[j] = U[(80 + j) * 1024 + col];
        q3[j] = U[(88 + j) * 1024 + col];
        q4[j] = U[(96 + j) * 1024 + col];
        q5[j] = U[(104 + j) * 1024 + col];
        q6[j] = U[(112 + j) * 1024 + col];
        q7[j] = U[(120 + j) * 1024 + col];
    }
    asm volatile(""
                 : "+v"(q0), "+v"(q1), "+v"(q2), "+v"(q3),
                   "+v"(q4), "+v"(q5), "+v"(q6), "+v"(q7));

    if (t < 128) sH[t] = 0u;
    float c = 0.f;
    __syncthreads();

    const uint4* hp4 = (const uint4*)sH;  // 32 chunks x (4 h2v) = 256 h
    float pc = P[col];
    for (int step = 0; step < 512; step++) {
        float pn = pc;
        if (step < 511) pn = P[(step + 1) * 1024 + col];
        float a0 = pc, a1 = 0.f, a2 = 0.f, a3 = 0.f;  // 4 indep dep-chains

        // kp [0,64) from LDS (lane-consecutive b32, conflict-free)
#pragma unroll
        for (int cch = 0; cch < 16; cch++) {
            uint4 hc = hp4[cch];
            const unsigned int* su = &sU[(4 * cch) * 256 + t];
            a0 = fdot2f(BC(hc.x), BC(su[0]), a0);
            a1 = fdot2f(BC(hc.y), BC(su[256]), a1);
            a2 = fdot2f(BC(hc.z), BC(su[512]), a2);
            a3 = fdot2f(BC(hc.w), BC(su[768]), a3);
        }
        // kp [64,128) from registers
#pragma unroll
        for (int cch = 16; cch < 32; cch++) {
            uint4 hc = hp4[cch];
            const int r0 = 4 * (cch - 16);
            a0 = fdot2f(BC(hc.x), BC(UAq(r0 + 0)), a0);
            a1 = fdot2f(BC(hc.y), BC(UAq(r0 + 1)), a1);
            a2 = fdot2f(BC(hc.z), BC(UAq(r0 + 2)), a2);
            a3 = fdot2f(BC(hc.w), BC(UAq(r0 + 3)), a3);
        }
        sZ[t] = (a0 + a1) + (a2 + a3);
        __syncthreads();

        unsigned long long* Hbuf = Hgd + ((step + 1) & 1) * 128;  // parity
        unsigned long long tag = (unsigned long long)(step + 1);
        if (t < 64) {
            float zi = sZ[t], zf = sZ[64 + t], zg = sZ[128 + t], zo = sZ[192 + t];
            float ig = 1.f / (1.f + __expf(-zi));
            float fg = 1.f / (1.f + __expf(-zf));
            float gg = 1.f - 2.f / (1.f + __expf(2.f * zg));   // tanh
            float og = 1.f / (1.f + __expf(-zo));
            c = fg * c + ig * gg;
            float h = og * (1.f - 2.f / (1.f + __expf(2.f * c)));
            O[step * 256 + (b << 6) + t] = h;
            sG[t] = h;  // wave 0 only: LDS ops below are same-wave ordered
            if (t < 32) {
                union { _Float16 hh[2]; unsigned int u; } pk;
                pk.hh[0] = (_Float16)sG[2 * t];
                pk.hh[1] = (_Float16)sG[2 * t + 1];
                unsigned long long v = (tag << 32) | (unsigned long long)pk.u;
                __hip_atomic_store(&Hbuf[(b << 5) + t], v, __ATOMIC_RELAXED,
                                   __HIP_MEMORY_SCOPE_AGENT);
            }
        }
        // single-round-trip poll: tag+data arrive in the same 8B load
        if (t < 128) {
            unsigned long long v;
            do {
                v = __hip_atomic_load(&Hbuf[t], __ATOMIC_RELAXED,
                                      __HIP_MEMORY_SCOPE_AGENT);
            } while ((v >> 32) != tag);
            sH[t] = (unsigned int)v;
        }
        __syncthreads();
        pc = pn;
    }
}

// ---------------------------------------------------------------------------
// concat: V[t][0:256] = F[t], V[t][256:512] = Bk[511-t]
// ---------------------------------------------------------------------------
__global__ __launch_bounds__(256) void concat_k(const float* __restrict__ F,
                                                const float* __restrict__ Bk,
                                                float* __restrict__ V) {
    int idx = blockIdx.x * 256 + threadIdx.x;  // < 262144
    int t = idx >> 9, d = idx & 511;
    V[idx] = (d < 256) ? F[t * 256 + d] : Bk[(511 - t) * 256 + d - 256];
}

// ---------------------------------------------------------------------------
// head: S[i][j] = sum_h tanh(HF[i][h] + MF[j][h]) * w[h] + outBias
// ---------------------------------------------------------------------------
__global__ __launch_bounds__(256) void head_kernel(const float* __restrict__ HF,
                                                   const float* __restrict__ MF,
                                                   const float* __restrict__ w,
                                                   const float* __restrict__ outb,
                                                   float* __restrict__ S) {
    int i = blockIdx.x;
    __shared__ float sHF[512], sW[512];
    int tid = threadIdx.x;
    sHF[tid] = HF[i * 512 + tid];
    sHF[tid + 256] = HF[i * 512 + 256 + tid];
    sW[tid] = w[tid];
    sW[tid + 256] = w[tid + 256];
    __syncthreads();
    int lane = tid & 63, wv = tid >> 6;
    float ob = outb[0];
    for (int j = wv; j < 512; j += 4) {
        const float* mf = MF + j * 512;
        float acc = 0.f;
#pragma unroll
        for (int r = 0; r < 8; r++) {
            int h = lane + 64 * r;
            float x = sHF[h] + mf[h];
            acc += sW[h] * (1.f - 2.f / (1.f + __expf(2.f * x)));
        }
#pragma unroll
        for (int off = 32; off; off >>= 1) acc += __shfl_down(acc, off);
        if (lane == 0) S[i * 512 + j] = acc + ob;
    }
}

// ---------------------------------------------------------------------------
extern "C" void kernel_launch(void* const* d_in, const int* in_sizes, int n_in,
                              void* d_out, int out_size, void* d_ws, size_t ws_size,
                              hipStream_t stream) {
    const float* emb      = (const float*)d_in[0];
    const float* W_f1     = (const float*)d_in[1];
    const float* U_f1     = (const float*)d_in[2];
    const float* b_f1     = (const float*)d_in[3];
    const float* W_b1     = (const float*)d_in[4];
    const float* U_b1     = (const float*)d_in[5];
    const float* b_b1     = (const float*)d_in[6];
    const float* W_f2     = (const float*)d_in[7];
    const float* U_f2     = (const float*)d_in[8];
    const float* b_f2     = (const float*)d_in[9];
    const float* W_b2     = (const float*)d_in[10];
    const float* U_b2     = (const float*)d_in[11];
    const float* b_b2     = (const float*)d_in[12];
    const float* FOH      = (const float*)d_in[13];
    const float* FOM      = (const float*)d_in[14];
    const float* hidBias  = (const float*)d_in[15];
    const float* outLayer = (const float*)d_in[16];
    const float* outBias  = (const float*)d_in[17];
    float* out = (float*)d_out;

    // workspace carve (16 MB total)
    unsigned int* uf = (unsigned int*)d_ws;          // 4 x 131072 uints = 2MB
    unsigned int* uf_f1 = uf;
    unsigned int* uf_b1 = uf + 131072;
    unsigned int* uf_f2 = uf + 262144;
    unsigned int* uf_b2 = uf + 393216;
    float* f = (float*)d_ws + 524288;
    float* P1f = f;                 // 512x1024
    float* P1b = f + 524288;
    float* P2f = f + 1048576;
    float* P2b = f + 1572864;
    float* rf1 = f + 2097152;       // 512x256
    float* rb1 = f + 2228224;
    float* rf2 = f + 2359296;
    float* rb2 = f + 2490368;
    float* v    = f + 2621440;      // 512x512
    float* hcat = f + 2883584;
    float* HFb  = f + 3145728;      // 512x512 (includes hidBias)
    float* MFb  = f + 3407872;
    // sync region aliases MFb (dead during both lstm dispatches: MFb is only
    // written by the 2nd-to-last gemm and read by head, both after lstm-2).
    // 2 dirs x 2 parity x 128 tagged 8B entries = 4KB.
    unsigned long long* sync = (unsigned long long*)(f + 3407872);

    prep_u<<<512, 256, 0, stream>>>(U_f1, uf_f1);
    prep_u<<<512, 256, 0, stream>>>(U_b1, uf_b1);
    prep_u<<<512, 256, 0, stream>>>(U_f2, uf_f2);
    prep_u<<<512, 256, 0, stream>>>(U_b2, uf_b2);

    dim3 g1(1024 / 64, 512 / 64);
    gemm_bias<<<g1, 256, 0, stream>>>(emb, W_f1, b_f1, P1f, 512, 1024, 256, 0);
    gemm_bias<<<g1, 256, 0, stream>>>(emb, W_b1, b_b1, P1b, 512, 1024, 256, 1);

    hipMemsetAsync(sync, 0, 4096, stream);
    lstm_quad<<<8, 256, 0, stream>>>(uf_f1, uf_b1, P1f, P1b, rf1, rb1, sync);

    concat_k<<<1024, 256, 0, stream>>>(rf1, rb1, v);

    gemm_bias<<<g1, 256, 0, stream>>>(v, W_f2, b_f2, P2f, 512, 1024, 512, 0);
    gemm_bias<<<g1, 256, 0, stream>>>(v, W_b2, b_b2, P2b, 512, 1024, 512, 1);

    hipMemsetAsync(sync, 0, 4096, stream);
    lstm_quad<<<8, 256, 0, stream>>>(uf_f2, uf_b2, P2f, P2b, rf2, rb2, sync);

    concat_k<<<1024, 256, 0, stream>>>(rf2, rb2, hcat);

    dim3 g2(512 / 64, 512 / 64);
    gemm_bias<<<g2, 256, 0, stream>>>(hcat, FOH, hidBias, HFb, 512, 512, 512, 0);
    gemm_bias<<<g2, 256, 0, stream>>>(hcat, FOM, nullptr, MFb, 512, 512, 512, 0);

    head_kernel<<<512, 256, 0, stream>>>(HFb, MFb, outLayer, outBias, out);
}